// Round 5
// baseline (241.621 us; speedup 1.0000x reference)
//
#include <hip/hip_runtime.h>
#include <hip/hip_fp16.h>
#include <stdint.h>

// DistMult relational decoder:
//   out[e] = sigmoid( sum_d z[src[e],d] * rel[rel_id[e],d] * z[dst[e],d] )
// N_NODES=100000, E=2000000, D=128, REL_TYPES=64, fp32 in/out.
//
// R5: R4 established the kernel is byte-rate-bound at ~3.5 TB/s on L2-miss
// gather traffic (FETCH=448 MB for 1.02 GB gathered; time scales with bytes).
// This round: bin edges by src-node range into 8 buckets (3.2 MB fp16 z-slice
// each). Main kernel assigns bucket = blockIdx%8; under the round-robin
// workgroup->XCD dispatch (the basis of the documented %8 swizzle heuristic),
// each XCD's src gathers then hit a slice resident in its own 4 MB L2.
// Binning = deterministic counting sort: block histograms -> one-block scan
// -> scatter with LDS cursors (no global atomics). Edge payload packed into
// 61 bits: src(17) | dst(17) | rel(6) | eid(21).
// dst gathers stay random (~225 MB fetch); src side drops ~210 -> ~26 MB.

#define HIST_BLOCKS 1024
#define BLOCK 256

// ---- pass 0: z fp32 -> fp16 into workspace (8 elems / thread) ----
__global__ __launch_bounds__(256) void convert_kernel(
    const float* __restrict__ z, __half* __restrict__ zh, int n8)
{
    const int i = blockIdx.x * blockDim.x + threadIdx.x;
    if (i >= n8) return;
    const float4 f0 = ((const float4*)z)[2 * i];
    const float4 f1 = ((const float4*)z)[2 * i + 1];
    union { __half2 h2[4]; uint4 u; } o;
    o.h2[0] = __floats2half2_rn(f0.x, f0.y);
    o.h2[1] = __floats2half2_rn(f0.z, f0.w);
    o.h2[2] = __floats2half2_rn(f1.x, f1.y);
    o.h2[3] = __floats2half2_rn(f1.z, f1.w);
    ((uint4*)zh)[i] = o.u;
}

__device__ __forceinline__ uint32_t bucket_of(uint32_t s, uint32_t nn) {
    uint32_t b = (s * 8u) / nn;
    return b > 7u ? 7u : b;
}

// ---- pass 1: per-block histogram of src buckets ----
__global__ __launch_bounds__(256) void hist_kernel(
    const int* __restrict__ src, int E, int nn, uint32_t* __restrict__ blockcounts)
{
    __shared__ uint32_t cnt[8];
    if (threadIdx.x < 8) cnt[threadIdx.x] = 0;
    __syncthreads();
    for (int i = blockIdx.x * BLOCK + threadIdx.x; i < E; i += HIST_BLOCKS * BLOCK) {
        uint32_t b = bucket_of((uint32_t)src[i], (uint32_t)nn);
        atomicAdd(&cnt[b], 1u);
    }
    __syncthreads();
    if (threadIdx.x < 8)
        blockcounts[blockIdx.x * 8 + threadIdx.x] = cnt[threadIdx.x];
}

// ---- pass 2: exclusive scan of (bucket-major) block counts, one block ----
__global__ __launch_bounds__(256) void scan_kernel(
    const uint32_t* __restrict__ blockcounts,
    uint32_t* __restrict__ blockbase,
    uint32_t* __restrict__ bucketbase,
    uint32_t* __restrict__ bucketcount,
    int E)
{
    const int t = threadIdx.x;
    const int NPT = (8 * HIST_BLOCKS) / 256;   // 32 entries per thread
    uint32_t local[NPT];
    uint32_t sum = 0;
    #pragma unroll
    for (int k = 0; k < NPT; k++) {
        int lin = t * NPT + k;                  // bucket-major linear index
        int b = lin >> 10, blk = lin & (HIST_BLOCKS - 1);
        local[k] = sum;                          // thread-local exclusive
        sum += blockcounts[blk * 8 + b];
    }
    __shared__ uint32_t part[256];
    part[t] = sum;
    __syncthreads();
    for (int off = 1; off < 256; off <<= 1) {    // Hillis-Steele inclusive
        uint32_t v = (t >= off) ? part[t - off] : 0;
        __syncthreads();
        part[t] += v;
        __syncthreads();
    }
    const uint32_t excl = part[t] - sum;
    __shared__ uint32_t bb[8];
    #pragma unroll
    for (int k = 0; k < NPT; k++) {
        int lin = t * NPT + k;
        int b = lin >> 10, blk = lin & (HIST_BLOCKS - 1);
        uint32_t base = excl + local[k];
        blockbase[blk * 8 + b] = base;
        if (blk == 0) bb[b] = base;
    }
    __syncthreads();
    if (t < 8) {
        bucketbase[t] = bb[t];
        uint32_t nb = (t < 7) ? bb[t + 1] : (uint32_t)E;
        bucketcount[t] = nb - bb[t];
    }
}

// ---- pass 3: scatter edges into bucket-contiguous packed array ----
__global__ __launch_bounds__(256) void scatter_kernel(
    const int* __restrict__ src, const int* __restrict__ dst,
    const int* __restrict__ relid, int E, int nn,
    const uint32_t* __restrict__ blockbase, uint64_t* __restrict__ binned)
{
    __shared__ uint32_t cur[8];
    if (threadIdx.x < 8) cur[threadIdx.x] = blockbase[blockIdx.x * 8 + threadIdx.x];
    __syncthreads();
    for (int i = blockIdx.x * BLOCK + threadIdx.x; i < E; i += HIST_BLOCKS * BLOCK) {
        uint32_t s = (uint32_t)src[i];
        uint32_t d = (uint32_t)dst[i];
        uint32_t r = (uint32_t)relid[i];
        uint32_t b = bucket_of(s, (uint32_t)nn);
        uint32_t pos = atomicAdd(&cur[b], 1u);   // LDS atomic
        binned[pos] = (uint64_t)s | ((uint64_t)d << 17)
                    | ((uint64_t)r << 34) | ((uint64_t)i << 40);
    }
}

// ---- pass 4: main gather kernel, bucket = blockIdx%8 (XCD affinity bet) ----
__global__ __launch_bounds__(256) void distmult_binned_kernel(
    const __half* __restrict__ zh,
    const uint64_t* __restrict__ binned,
    const uint32_t* __restrict__ bucketbase,
    const uint32_t* __restrict__ bucketcount,
    const float* __restrict__ rel,
    float* __restrict__ out)
{
    const int bkt   = blockIdx.x & 7;
    const int chunk = blockIdx.x >> 3;
    const int g     = threadIdx.x >> 4;
    const int lane  = threadIdx.x & 15;
    const uint32_t cnt = bucketcount[bkt];
    const uint32_t el  = (uint32_t)chunk * 16u + (uint32_t)g;
    if (el >= cnt) return;

    const uint64_t p = binned[bucketbase[bkt] + el];
    const uint32_t s   = (uint32_t)p & 0x1FFFFu;
    const uint32_t d   = (uint32_t)(p >> 17) & 0x1FFFFu;
    const uint32_t r   = (uint32_t)(p >> 34) & 0x3Fu;
    const uint32_t eid = (uint32_t)(p >> 40);

    union { uint4 u; __half2 h2[4]; } A, B;
    A.u = ((const uint4*)(zh + (size_t)s * 128))[lane];
    B.u = ((const uint4*)(zh + (size_t)d * 128))[lane];
    const float4* rr = (const float4*)(rel + (size_t)r * 128);
    const float4 r0 = rr[2 * lane];
    const float4 r1 = rr[2 * lane + 1];

    const float2 a0 = __half22float2(A.h2[0]);
    const float2 a1 = __half22float2(A.h2[1]);
    const float2 a2 = __half22float2(A.h2[2]);
    const float2 a3 = __half22float2(A.h2[3]);
    const float2 b0 = __half22float2(B.h2[0]);
    const float2 b1 = __half22float2(B.h2[1]);
    const float2 b2 = __half22float2(B.h2[2]);
    const float2 b3 = __half22float2(B.h2[3]);

    float v = a0.x * r0.x * b0.x + a0.y * r0.y * b0.y
            + a1.x * r0.z * b1.x + a1.y * r0.w * b1.y
            + a2.x * r1.x * b2.x + a2.y * r1.y * b2.y
            + a3.x * r1.z * b3.x + a3.y * r1.w * b3.y;

    #pragma unroll
    for (int off = 8; off > 0; off >>= 1)
        v += __shfl_down(v, off, 16);

    if (lane == 0)
        out[eid] = 1.0f / (1.0f + __expf(-v));
}

// ---- fallback kernels (R4 / R3 structure) ----
__global__ __launch_bounds__(256) void distmult_f16_kernel(
    const __half* __restrict__ zh,
    const int* __restrict__ src_idx, const int* __restrict__ dst_idx,
    const int* __restrict__ rel_id, const float* __restrict__ rel,
    float* __restrict__ out, int E)
{
    const int gtid = blockIdx.x * blockDim.x + threadIdx.x;
    const int e = gtid >> 4;
    const int lane = threadIdx.x & 15;
    if (e >= E) return;
    const int s = src_idx[e], d = dst_idx[e], r = rel_id[e];
    union { uint4 u; __half2 h2[4]; } A, B;
    A.u = ((const uint4*)(zh + (size_t)s * 128))[lane];
    B.u = ((const uint4*)(zh + (size_t)d * 128))[lane];
    const float4* rr = (const float4*)(rel + (size_t)r * 128);
    const float4 r0 = rr[2 * lane];
    const float4 r1 = rr[2 * lane + 1];
    const float2 a0 = __half22float2(A.h2[0]), a1 = __half22float2(A.h2[1]);
    const float2 a2 = __half22float2(A.h2[2]), a3 = __half22float2(A.h2[3]);
    const float2 b0 = __half22float2(B.h2[0]), b1 = __half22float2(B.h2[1]);
    const float2 b2 = __half22float2(B.h2[2]), b3 = __half22float2(B.h2[3]);
    float v = a0.x * r0.x * b0.x + a0.y * r0.y * b0.y
            + a1.x * r0.z * b1.x + a1.y * r0.w * b1.y
            + a2.x * r1.x * b2.x + a2.y * r1.y * b2.y
            + a3.x * r1.z * b3.x + a3.y * r1.w * b3.y;
    #pragma unroll
    for (int off = 8; off > 0; off >>= 1) v += __shfl_down(v, off, 16);
    if (lane == 0) out[e] = 1.0f / (1.0f + __expf(-v));
}

__global__ __launch_bounds__(256) void distmult_f32_kernel(
    const float* __restrict__ z,
    const int* __restrict__ src_idx, const int* __restrict__ dst_idx,
    const int* __restrict__ rel_id, const float* __restrict__ rel,
    float* __restrict__ out, int E)
{
    const int gtid = blockIdx.x * blockDim.x + threadIdx.x;
    const int e = gtid >> 4;
    const int lane = threadIdx.x & 15;
    if (e >= E) return;
    const int s = src_idx[e], d = dst_idx[e], r = rel_id[e];
    const float4* zs = (const float4*)(z + (size_t)s * 128);
    const float4* zd = (const float4*)(z + (size_t)d * 128);
    const float4* rr = (const float4*)(rel + (size_t)r * 128);
    const float4 a0 = zs[lane], a1 = zs[lane + 16];
    const float4 b0 = zd[lane], b1 = zd[lane + 16];
    const float4 c0 = rr[lane], c1 = rr[lane + 16];
    float v = a0.x * c0.x * b0.x + a0.y * c0.y * b0.y
            + a0.z * c0.z * b0.z + a0.w * c0.w * b0.w
            + a1.x * c1.x * b1.x + a1.y * c1.y * b1.y
            + a1.z * c1.z * b1.z + a1.w * c1.w * b1.w;
    #pragma unroll
    for (int off = 8; off > 0; off >>= 1) v += __shfl_down(v, off, 16);
    if (lane == 0) out[e] = 1.0f / (1.0f + __expf(-v));
}

extern "C" void kernel_launch(void* const* d_in, const int* in_sizes, int n_in,
                              void* d_out, int out_size, void* d_ws, size_t ws_size,
                              hipStream_t stream) {
    const float* z      = (const float*)d_in[0];
    const int*   eidx   = (const int*)d_in[1];   // [2, E] flat: src then dst
    const int*   relid  = (const int*)d_in[2];
    const float* rel    = (const float*)d_in[3];
    float*       out    = (float*)d_out;

    const int nz = in_sizes[0];          // N_NODES * 128
    const int E  = in_sizes[2];          // 2,000,000
    const int nn = nz / 128;             // N_NODES
    const int* src = eidx;
    const int* dst = eidx + E;

    // ws layout
    const size_t sz_zh      = (size_t)nz * sizeof(__half);
    const size_t off_binned = (sz_zh + 255) & ~(size_t)255;
    const size_t sz_binned  = (size_t)E * 8;
    const size_t off_bc     = off_binned + sz_binned;
    const size_t sz_bc      = (size_t)HIST_BLOCKS * 8 * 4;
    const size_t off_bb     = off_bc + sz_bc;
    const size_t off_bkb    = off_bb + sz_bc;
    const size_t off_bkc    = off_bkb + 64;
    const size_t need       = off_bkc + 64;

    const bool bits_ok = (nn <= 131072) && (E <= (1 << 21)) && (nz % 8 == 0);

    if (ws_size >= need && bits_ok) {
        char* ws = (char*)d_ws;
        __half*   zh          = (__half*)(ws);
        uint64_t* binned      = (uint64_t*)(ws + off_binned);
        uint32_t* blockcounts = (uint32_t*)(ws + off_bc);
        uint32_t* blockbase   = (uint32_t*)(ws + off_bb);
        uint32_t* bucketbase  = (uint32_t*)(ws + off_bkb);
        uint32_t* bucketcount = (uint32_t*)(ws + off_bkc);

        const int n8 = nz / 8;
        convert_kernel<<<(n8 + 255) / 256, 256, 0, stream>>>(z, zh, n8);
        hist_kernel<<<HIST_BLOCKS, BLOCK, 0, stream>>>(src, E, nn, blockcounts);
        scan_kernel<<<1, 256, 0, stream>>>(blockcounts, blockbase,
                                           bucketbase, bucketcount, E);
        scatter_kernel<<<HIST_BLOCKS, BLOCK, 0, stream>>>(src, dst, relid, E, nn,
                                                          blockbase, binned);
        // capacity: expected E/8 per bucket; +~14% slack (randint uniform,
        // sigma ~= 470 -> slack is ~60 sigma)
        const int cap_edges = E / 8 + E / 64 + 1024;
        const int nblk_per  = (cap_edges + 15) / 16;
        distmult_binned_kernel<<<8 * nblk_per, 256, 0, stream>>>(
            zh, binned, bucketbase, bucketcount, rel, out);
    } else if (ws_size >= sz_zh && nz % 8 == 0) {
        __half* zh = (__half*)d_ws;
        const int n8 = nz / 8;
        convert_kernel<<<(n8 + 255) / 256, 256, 0, stream>>>(z, zh, n8);
        const int blocks = (E * 16 + 255) / 256;
        distmult_f16_kernel<<<blocks, 256, 0, stream>>>(zh, src, dst, relid, rel, out, E);
    } else {
        const int blocks = (E * 16 + 255) / 256;
        distmult_f32_kernel<<<blocks, 256, 0, stream>>>(z, src, dst, relid, rel, out, E);
    }
}

// Round 6
// 225.558 us; speedup vs baseline: 1.0712x; 1.0712x over previous
//
#include <hip/hip_runtime.h>
#include <hip/hip_fp16.h>
#include <stdint.h>

// DistMult relational decoder:
//   out[e] = sigmoid( sum_d z[src[e],d] * rel[rel_id[e],d] * z[dst[e],d] )
// N_NODES=100000, E=2000000, D=128, REL_TYPES=64, fp32 in/out.
//
// R6: revert R5's binning (aux passes cost > locality gain; dst misses
// dominate and are irreducible at this E/N ratio). Attack TCC *hit*
// bandwidth instead: R4 demanded ~2.06 GB at the TCC (1.02 GB z-fp16
// gathers + 1.02 GB rel fp32 reads, all L2-hit). Convert rel to fp16 and
// stage per-block in LDS (16 KB) -> rel leaves the TCC path entirely,
// halving demanded bytes. 2 edges per 16-lane group keeps 4 independent
// global uint4 gathers in flight per lane (same MLP as R4). Coalesced
// float2 out-write per group.

// ---- fp32 -> fp16 converter (8 elems / thread), used for z and rel ----
__global__ __launch_bounds__(256) void convert_kernel(
    const float* __restrict__ x, __half* __restrict__ xh, int n8)
{
    const int i = blockIdx.x * blockDim.x + threadIdx.x;
    if (i >= n8) return;
    const float4 f0 = ((const float4*)x)[2 * i];
    const float4 f1 = ((const float4*)x)[2 * i + 1];
    union { __half2 h2[4]; uint4 u; } o;
    o.h2[0] = __floats2half2_rn(f0.x, f0.y);
    o.h2[1] = __floats2half2_rn(f0.z, f0.w);
    o.h2[2] = __floats2half2_rn(f1.x, f1.y);
    o.h2[3] = __floats2half2_rn(f1.z, f1.w);
    ((uint4*)xh)[i] = o.u;
}

// ---- main: z fp16 gathers + rel fp16 from LDS, 2 edges / 16-lane group ----
__global__ __launch_bounds__(256) void distmult_f16_lds_kernel(
    const __half* __restrict__ zh,
    const int* __restrict__ src_idx,
    const int* __restrict__ dst_idx,
    const int* __restrict__ rel_id,
    const __half* __restrict__ relh,   // [64*128] fp16
    float* __restrict__ out,
    int E)
{
    __shared__ uint4 rel_lds[1024];    // 64 rows * 16 uint4 = 16 KB
    {
        const uint4* rsrc = (const uint4*)relh;
        #pragma unroll
        for (int k = 0; k < 4; k++)
            rel_lds[threadIdx.x + 256 * k] = rsrc[threadIdx.x + 256 * k];
    }
    __syncthreads();

    const int gtid = blockIdx.x * blockDim.x + threadIdx.x;
    const int g    = gtid >> 4;          // 16-lane group id
    const int lane = threadIdx.x & 15;
    const int e0   = g * 2;
    const int e1   = e0 + 1;
    if (e0 >= E) return;
    const bool has1 = (e1 < E);

    const int s0 = src_idx[e0], d0 = dst_idx[e0], r0 = rel_id[e0];
    const int s1 = has1 ? src_idx[e1] : s0;
    const int d1 = has1 ? dst_idx[e1] : d0;
    const int r1 = has1 ? rel_id[e1]  : r0;

    // 4 independent global 16 B gathers in flight per lane
    union { uint4 u; __half2 h2[4]; } A0, B0, A1, B1, R0, R1;
    A0.u = ((const uint4*)(zh + (size_t)s0 * 128))[lane];
    B0.u = ((const uint4*)(zh + (size_t)d0 * 128))[lane];
    A1.u = ((const uint4*)(zh + (size_t)s1 * 128))[lane];
    B1.u = ((const uint4*)(zh + (size_t)d1 * 128))[lane];
    R0.u = rel_lds[r0 * 16 + lane];
    R1.u = rel_lds[r1 * 16 + lane];

    float v0 = 0.f, v1 = 0.f;
    #pragma unroll
    for (int j = 0; j < 4; j++) {
        const float2 a0 = __half22float2(A0.h2[j]);
        const float2 b0 = __half22float2(B0.h2[j]);
        const float2 r0f = __half22float2(R0.h2[j]);
        v0 += a0.x * r0f.x * b0.x + a0.y * r0f.y * b0.y;
        const float2 a1 = __half22float2(A1.h2[j]);
        const float2 b1 = __half22float2(B1.h2[j]);
        const float2 r1f = __half22float2(R1.h2[j]);
        v1 += a1.x * r1f.x * b1.x + a1.y * r1f.y * b1.y;
    }

    #pragma unroll
    for (int off = 8; off > 0; off >>= 1) {
        v0 += __shfl_down(v0, off, 16);
        v1 += __shfl_down(v1, off, 16);
    }

    if (lane == 0) {
        const float o0 = 1.0f / (1.0f + __expf(-v0));
        if (has1) {
            const float o1 = 1.0f / (1.0f + __expf(-v1));
            *((float2*)(out + e0)) = make_float2(o0, o1);  // e0 even -> 8B aligned
        } else {
            out[e0] = o0;
        }
    }
}

// ---- fallback: R4 kernel (z fp16, rel fp32 from cache) ----
__global__ __launch_bounds__(256) void distmult_f16_kernel(
    const __half* __restrict__ zh,
    const int* __restrict__ src_idx, const int* __restrict__ dst_idx,
    const int* __restrict__ rel_id, const float* __restrict__ rel,
    float* __restrict__ out, int E)
{
    const int gtid = blockIdx.x * blockDim.x + threadIdx.x;
    const int e = gtid >> 4;
    const int lane = threadIdx.x & 15;
    if (e >= E) return;
    const int s = src_idx[e], d = dst_idx[e], r = rel_id[e];
    union { uint4 u; __half2 h2[4]; } A, B;
    A.u = ((const uint4*)(zh + (size_t)s * 128))[lane];
    B.u = ((const uint4*)(zh + (size_t)d * 128))[lane];
    const float4* rr = (const float4*)(rel + (size_t)r * 128);
    const float4 r0 = rr[2 * lane];
    const float4 r1 = rr[2 * lane + 1];
    const float2 a0 = __half22float2(A.h2[0]), a1 = __half22float2(A.h2[1]);
    const float2 a2 = __half22float2(A.h2[2]), a3 = __half22float2(A.h2[3]);
    const float2 b0 = __half22float2(B.h2[0]), b1 = __half22float2(B.h2[1]);
    const float2 b2 = __half22float2(B.h2[2]), b3 = __half22float2(B.h2[3]);
    float v = a0.x * r0.x * b0.x + a0.y * r0.y * b0.y
            + a1.x * r0.z * b1.x + a1.y * r0.w * b1.y
            + a2.x * r1.x * b2.x + a2.y * r1.y * b2.y
            + a3.x * r1.z * b3.x + a3.y * r1.w * b3.y;
    #pragma unroll
    for (int off = 8; off > 0; off >>= 1) v += __shfl_down(v, off, 16);
    if (lane == 0) out[e] = 1.0f / (1.0f + __expf(-v));
}

// ---- fallback: pure fp32 ----
__global__ __launch_bounds__(256) void distmult_f32_kernel(
    const float* __restrict__ z,
    const int* __restrict__ src_idx, const int* __restrict__ dst_idx,
    const int* __restrict__ rel_id, const float* __restrict__ rel,
    float* __restrict__ out, int E)
{
    const int gtid = blockIdx.x * blockDim.x + threadIdx.x;
    const int e = gtid >> 4;
    const int lane = threadIdx.x & 15;
    if (e >= E) return;
    const int s = src_idx[e], d = dst_idx[e], r = rel_id[e];
    const float4* zs = (const float4*)(z + (size_t)s * 128);
    const float4* zd = (const float4*)(z + (size_t)d * 128);
    const float4* rr = (const float4*)(rel + (size_t)r * 128);
    const float4 a0 = zs[lane], a1 = zs[lane + 16];
    const float4 b0 = zd[lane], b1 = zd[lane + 16];
    const float4 c0 = rr[lane], c1 = rr[lane + 16];
    float v = a0.x * c0.x * b0.x + a0.y * c0.y * b0.y
            + a0.z * c0.z * b0.z + a0.w * c0.w * b0.w
            + a1.x * c1.x * b1.x + a1.y * c1.y * b1.y
            + a1.z * c1.z * b1.z + a1.w * c1.w * b1.w;
    #pragma unroll
    for (int off = 8; off > 0; off >>= 1) v += __shfl_down(v, off, 16);
    if (lane == 0) out[e] = 1.0f / (1.0f + __expf(-v));
}

extern "C" void kernel_launch(void* const* d_in, const int* in_sizes, int n_in,
                              void* d_out, int out_size, void* d_ws, size_t ws_size,
                              hipStream_t stream) {
    const float* z     = (const float*)d_in[0];
    const int*   eidx  = (const int*)d_in[1];   // [2, E] flat: src then dst
    const int*   relid = (const int*)d_in[2];
    const float* rel   = (const float*)d_in[3];
    float*       out   = (float*)d_out;

    const int nz   = in_sizes[0];        // N_NODES * 128
    const int E    = in_sizes[2];        // 2,000,000
    const int nrel = in_sizes[3];        // 64 * 128 = 8192
    const int* src = eidx;
    const int* dst = eidx + E;

    const size_t sz_zh   = (size_t)nz * sizeof(__half);
    const size_t off_rh  = (sz_zh + 255) & ~(size_t)255;
    const size_t sz_rh   = (size_t)nrel * sizeof(__half);
    const size_t need    = off_rh + sz_rh;

    const bool rel_ok = (nrel == 64 * 128) && (nrel % 8 == 0);

    if (ws_size >= need && nz % 8 == 0 && rel_ok) {
        __half* zh = (__half*)d_ws;
        __half* rh = (__half*)((char*)d_ws + off_rh);
        const int n8z = nz / 8, n8r = nrel / 8;
        convert_kernel<<<(n8z + 255) / 256, 256, 0, stream>>>(z, zh, n8z);
        convert_kernel<<<(n8r + 255) / 256, 256, 0, stream>>>(rel, rh, n8r);
        const int groups = (E + 1) / 2;
        const int blocks = (groups * 16 + 255) / 256;
        distmult_f16_lds_kernel<<<blocks, 256, 0, stream>>>(
            zh, src, dst, relid, rh, out, E);
    } else if (ws_size >= sz_zh && nz % 8 == 0) {
        __half* zh = (__half*)d_ws;
        const int n8z = nz / 8;
        convert_kernel<<<(n8z + 255) / 256, 256, 0, stream>>>(z, zh, n8z);
        const int blocks = (E * 16 + 255) / 256;
        distmult_f16_kernel<<<blocks, 256, 0, stream>>>(zh, src, dst, relid, rel, out, E);
    } else {
        const int blocks = (E * 16 + 255) / 256;
        distmult_f32_kernel<<<blocks, 256, 0, stream>>>(z, src, dst, relid, rel, out, E);
    }
}